// Round 9
// baseline (96.806 us; speedup 1.0000x reference)
//
#include <hip/hip_runtime.h>
#include <math.h>

#define TOKENS 16384
#define DIM 4096
#define NE 64
#define BM 32
#define NKT 64
#define NBLK 512

// ws float offsets
#define WS_META  256                       // float4 per token: 65536 floats
#define WS_PART  65792                     // 512 blocks x 192 floats
#define WS_WST   164096                    // 524288 ushorts = W f16 2-plane frag-linear

typedef __attribute__((ext_vector_type(8))) _Float16 f16x8;
typedef __attribute__((ext_vector_type(16))) float f32x16;

// W [4096][64] f32 -> wst: per kt (64), 16 fragments of 1 KB in glds-linear order.
//   slot = frag*64 + lane, frag = s*4 + p*2 + eh  (s:kstep 0..3, p:plane, eh:expert half)
//   wst[kt*8192 + slot*8 + j] = plane-p f16 of 4096*W[kt*64 + s*16 + (lane>>5)*8 + j][eh*32 + (lane&31)]
__global__ __launch_bounds__(256) void wconv(const float* __restrict__ W,
                                             ushort* __restrict__ wst) {
    __shared__ float t[64][68];
    const int kt = blockIdx.x, tid = threadIdx.x;
    #pragma unroll
    for (int i = 0; i < 4; i++) {
        int idx = tid + i * 256;
        int r = idx >> 4, c4 = idx & 15;
        float4 v = *(const float4*)(W + (size_t)(kt * 64 + r) * NE + c4 * 4);
        *(float4*)(&t[r][c4 * 4]) = v;
    }
    __syncthreads();
    #pragma unroll
    for (int it = 0; it < 4; it++) {
        int slot = it * 256 + tid;          // 0..1023
        int frag = slot >> 6, lane = slot & 63;
        int s = frag >> 2, p = (frag >> 1) & 1, eh = frag & 1;
        int e  = eh * 32 + (lane & 31);
        int kl = s * 16 + (lane >> 5) * 8;
        f16x8 o;
        #pragma unroll
        for (int j = 0; j < 8; j++) {
            float f = 4096.0f * t[kl + j][e];
            _Float16 hh = (_Float16)f;
            o[j] = p ? (_Float16)(f - (float)hh) : hh;
        }
        *(f16x8*)(wst + (size_t)kt * 8192 + (size_t)slot * 8) = o;
    }
}

// LDS buffer (24576 B):
//   x f32 [0,8192):  off(r,cs) = (r>>3)*2048 + (cs&1)*1024 + (r&7)*128 + (cs>>1)*16
//                    stored chunk cs holds logical chunk c = (cs&1) | (((cs>>1)^(r&7))<<1)
//   W     [8192,24576): 8192 + slot*16 (glds-linear, frag layout per wconv)
__global__ __launch_bounds__(256, 2) void gate_main(const float* __restrict__ x,
        const ushort* __restrict__ wst, const float* __restrict__ bias,
        float* __restrict__ ws) {

    __shared__ __align__(16) char smem[3][24576];
    __shared__ float tmax[BM], tinv[BM];
    __shared__ float pp[4][NE];
    __shared__ float sg0[BM], sg1[BM];
    __shared__ int   si0[BM], si1[BM];

    const int tid = threadIdx.x, wave = tid >> 6, lane = tid & 63;
    const int l31 = lane & 31, khf = lane >> 5;
    const int eh = wave & 1;           // expert half
    const int kh = wave >> 1;          // K half
    const int tb = blockIdx.x * BM;
    const int blk = blockIdx.x;

    f32x16 acc;
    #pragma unroll
    for (int i = 0; i < 16; i++) acc[i] = 0.0f;

    auto issue_x = [&](char* B, int kt) {
        #pragma unroll
        for (int q = 0; q < 2; q++) {
            int cs = ((lane & 7) << 1) | q;              // stored chunk
            int r  = (wave << 3) | (lane >> 3);          // row 0..31
            int cl = (cs & 1) | ((((cs >> 1) ^ (r & 7))) << 1);
            const float* src = x + (size_t)(tb + r) * DIM + kt * 64 + cl * 4;
            __builtin_amdgcn_global_load_lds(
                (const __attribute__((address_space(1))) uint*)src,
                (__attribute__((address_space(3))) uint*)
                    (B + wave * 2048 + q * 1024 + lane * 16), 16, 0, 0);
        }
    };
    auto issue_w = [&](char* B, int kt) {
        #pragma unroll
        for (int q = 0; q < 4; q++)
            __builtin_amdgcn_global_load_lds(
                (const __attribute__((address_space(1))) uint*)
                    (wst + (size_t)kt * 8192 + q * 2048 + tid * 8),
                (__attribute__((address_space(3))) uint*)
                    (B + 8192 + q * 4096 + tid * 16), 16, 0, 0);
    };
    auto compute = [&](const char* B) {
        #pragma unroll
        for (int si = 0; si < 2; si++) {
            int s = kh * 2 + si;
            int c0 = s * 4 + khf * 2;                    // even logical chunk
            uint cs_hi = (uint)((c0 >> 1) ^ (l31 & 7));
            uint base = (uint)(l31 >> 3) * 2048 + (uint)(l31 & 7) * 128 + cs_hi * 16;
            float4 A0 = *(const float4*)(B + base);
            float4 A1 = *(const float4*)(B + base + 1024);
            f16x8 ah, am;
            {
                float f[8] = {A0.x, A0.y, A0.z, A0.w, A1.x, A1.y, A1.z, A1.w};
                #pragma unroll
                for (int j = 0; j < 8; j++) {
                    float v = 512.0f * f[j];
                    _Float16 hh = (_Float16)v;
                    ah[j] = hh;
                    am[j] = (_Float16)(v - (float)hh);
                }
            }
            const char* Wb = B + 8192 + (size_t)(s * 4 + eh) * 1024 + lane * 16;
            f16x8 wh = *(const f16x8*)(Wb);
            f16x8 wm = *(const f16x8*)(Wb + 2048);
            acc = __builtin_amdgcn_mfma_f32_32x32x16_f16(ah, wh, acc, 0, 0, 0);
            acc = __builtin_amdgcn_mfma_f32_32x32x16_f16(am, wh, acc, 0, 0, 0);
            acc = __builtin_amdgcn_mfma_f32_32x32x16_f16(ah, wm, acc, 0, 0, 0);
        }
    };

    // prologue: depth-2 prefetch (12 glds ops outstanding per wave)
    issue_x(smem[0], 0);
    issue_w(smem[0], 0);
    issue_x(smem[1], 1);
    issue_w(smem[1], 1);

    // main loop: counted vmcnt keeps next tile's 6 loads in flight across the barrier
    for (int kt = 0; kt < NKT - 1; kt++) {
        asm volatile("s_waitcnt vmcnt(6)" ::: "memory");
        __builtin_amdgcn_s_barrier();
        if (kt + 2 < NKT) {
            char* nb = smem[(kt + 2) % 3];
            issue_x(nb, kt + 2);
            issue_w(nb, kt + 2);
        }
        compute(smem[kt % 3]);
    }
    // last tile: full drain
    asm volatile("s_waitcnt vmcnt(0)" ::: "memory");
    __builtin_amdgcn_s_barrier();
    compute(smem[(NKT - 1) % 3]);
    __syncthreads();

    // epilogue: logits into LDS (aliased onto buf0)
    float* lgf = (float*)smem[0];     // lg[32][68]
    const float scale = 1.0f / 2097152.0f;   // 2^-21 = 1/(512*4096)
    {
        int col = eh * 32 + l31;
        if (kh == 0) {
            float b = bias[col];
            #pragma unroll
            for (int r = 0; r < 16; r++) {
                int row = (r & 3) + 8 * (r >> 2) + 4 * khf;
                lgf[row * 68 + col] = acc[r] * scale + b;
            }
        }
    }
    __syncthreads();
    {
        int col = eh * 32 + l31;
        if (kh == 1) {
            #pragma unroll
            for (int r = 0; r < 16; r++) {
                int row = (r & 3) + 8 * (r >> 2) + 4 * khf;
                lgf[row * 68 + col] += acc[r] * scale;
            }
        }
    }
    __syncthreads();

    // per-token softmax + top-2 (threads 0..31) — no atomics, stash picks in LDS
    if (tid < BM) {
        const int t = tid;
        float m = -INFINITY;
        #pragma unroll
        for (int e = 0; e < NE; e++) m = fmaxf(m, lgf[t * 68 + e]);
        float s = 0.0f;
        float v0 = -INFINITY, v1 = -INFINITY;
        int i0 = 0, i1 = 1;
        #pragma unroll
        for (int e = 0; e < NE; e++) {
            float l = lgf[t * 68 + e];
            s += expf(l - m);
            if (l > v0) { v1 = v0; i1 = i0; v0 = l; i0 = e; }
            else if (l > v1) { v1 = l; i1 = e; }
        }
        float inv = 1.0f / s;
        tmax[t] = m; tinv[t] = inv;
        float g0 = expf(v0 - m) * inv;
        float g1 = expf(v1 - m) * inv;
        sg0[t] = g0; sg1[t] = g1; si0[t] = i0; si1[t] = i1;
        float4 mt4;
        mt4.x = __int_as_float(i0);
        mt4.y = __int_as_float(i1);
        mt4.z = g0; mt4.w = g1;
        ((float4*)(ws + WS_META))[tb + t] = mt4;
    }
    __syncthreads();

    // per-expert gate-score partial sums (density_proxy numerator)
    {
        int e = tid & 63;
        int grp = tid >> 6;    // 0..3, 8 tokens each
        float p = 0.0f;
        #pragma unroll
        for (int r = 0; r < 8; r++) {
            int t = grp * 8 + r;
            p += expf(lgf[t * 68 + e] - tmax[t]) * tinv[t];
        }
        pp[grp][e] = p;
    }
    __syncthreads();

    // deterministic per-block partials: [blk][0:64)=denom, [64:128)=proxy, [128:192)=count
    if (tid < NE) {
        int e = tid;
        float d = 0.0f, c = 0.0f;
        #pragma unroll
        for (int t = 0; t < BM; t++) {
            if (si0[t] == e) { d += sg0[t]; c += 1.0f; }
            if (si1[t] == e) { d += sg1[t]; c += 1.0f; }
        }
        float pr = pp[0][e] + pp[1][e] + pp[2][e] + pp[3][e];
        float* P = ws + WS_PART + (size_t)blk * 192;
        P[e]       = d;
        P[64 + e]  = pr;
        P[128 + e] = c;
    }
}

// finals: ws[0:64)=denom, ws[64:128)=proxy, ws[128:192)=count
__global__ __launch_bounds__(64) void gate_reduce(const float* __restrict__ part,
                                                  float* __restrict__ ws) {
    const int f = blockIdx.x;      // 0..191
    const int lane = threadIdx.x;  // 0..63
    float s = 0.0f;
    #pragma unroll
    for (int j = 0; j < 8; j++)
        s += part[(size_t)(lane * 8 + j) * 192 + f];
    #pragma unroll
    for (int off = 32; off; off >>= 1) s += __shfl_down(s, off);
    if (lane == 0) ws[f] = s;
}

__global__ __launch_bounds__(256) void gate_write(const float* __restrict__ ws,
                                                  float* __restrict__ out) {
    const float CAP = 16384.0f;
    int tid = threadIdx.x;
    int tl = tid >> 4;
    int e4 = (tid & 15) * 4;
    int t = blockIdx.x * 16 + tl;
    float4 mt = ((const float4*)(ws + WS_META))[t];
    int i0 = __float_as_int(mt.x), i1 = __float_as_int(mt.y);
    float s0 = mt.z * CAP / (ws[i0] + 1e-6f);
    float s1 = mt.w * CAP / (ws[i1] + 1e-6f);
    float4 v = {0.0f, 0.0f, 0.0f, 0.0f};
    float* vp = (float*)&v;
    #pragma unroll
    for (int j = 0; j < 4; j++) {
        int e = e4 + j;
        vp[j] = (e == i0) ? s0 : ((e == i1) ? s1 : 0.0f);
    }
    *(float4*)(out + (size_t)t * NE + e4) = v;
}

__global__ void gate_loss(const float* __restrict__ ws, float* __restrict__ out) {
    int e = threadIdx.x;
    float v = ws[64 + e] * ws[128 + e];
    #pragma unroll
    for (int off = 32; off; off >>= 1) v += __shfl_down(v, off);
    if (e == 0) {
        out[(size_t)TOKENS * NE] = 64.0f * v / (16384.0f * 16384.0f);
    }
}

extern "C" void kernel_launch(void* const* d_in, const int* in_sizes, int n_in,
                              void* d_out, int out_size, void* d_ws, size_t ws_size,
                              hipStream_t stream) {
    const float* x = (const float*)d_in[0];
    const float* W = (const float*)d_in[1];
    const float* b = (const float*)d_in[2];
    float* out = (float*)d_out;
    float* ws = (float*)d_ws;
    ushort* wst = (ushort*)(ws + WS_WST);

    hipLaunchKernelGGL(wconv, dim3(64), dim3(256), 0, stream, W, wst);
    hipLaunchKernelGGL(gate_main, dim3(NBLK), dim3(256), 0, stream, x, wst, b, ws);
    hipLaunchKernelGGL(gate_reduce, dim3(192), dim3(64), 0, stream,
                       ws + WS_PART, ws);
    hipLaunchKernelGGL(gate_write, dim3(TOKENS / 16), dim3(256), 0, stream, ws, out);
    hipLaunchKernelGGL(gate_loss, dim3(1), dim3(64), 0, stream, ws, out);
}

// Round 10
// 90.034 us; speedup vs baseline: 1.0752x; 1.0752x over previous
//
#include <hip/hip_runtime.h>
#include <math.h>

#define TOKENS 16384
#define DIM 4096
#define NE 64
#define BM 32
#define NKT 64
#define NBLK 512

// ws float offsets
#define WS_META  256                       // float4 per token: 65536 floats
#define WS_PART  65792                     // 512 blocks x 192 floats
#define WS_WST   164096                    // 524288 ushorts = W f16 2-plane frag-linear

typedef __attribute__((ext_vector_type(8))) _Float16 f16x8;
typedef __attribute__((ext_vector_type(16))) float f32x16;

// W [4096][64] f32 -> wst: per kt (64), 16 fragments of 1 KB.
//   frag = s*4 + p*2 + eh  (s: k-step 0..3, p: plane, eh: expert half)
//   wst[kt*8192 + frag*512 + lane*8 + j] =
//     plane-p f16 of 4096*W[kt*64 + s*16 + (lane>>5)*8 + j][eh*32 + (lane&31)]
__global__ __launch_bounds__(256) void wconv(const float* __restrict__ W,
                                             ushort* __restrict__ wst) {
    __shared__ float t[64][68];
    const int kt = blockIdx.x, tid = threadIdx.x;
    #pragma unroll
    for (int i = 0; i < 4; i++) {
        int idx = tid + i * 256;
        int r = idx >> 4, c4 = idx & 15;
        float4 v = *(const float4*)(W + (size_t)(kt * 64 + r) * NE + c4 * 4);
        *(float4*)(&t[r][c4 * 4]) = v;
    }
    __syncthreads();
    #pragma unroll
    for (int it = 0; it < 4; it++) {
        int slot = it * 256 + tid;          // 0..1023
        int frag = slot >> 6, lane = slot & 63;
        int s = frag >> 2, p = (frag >> 1) & 1, eh = frag & 1;
        int e  = eh * 32 + (lane & 31);
        int kl = s * 16 + (lane >> 5) * 8;
        f16x8 o;
        #pragma unroll
        for (int j = 0; j < 8; j++) {
            float f = 4096.0f * t[kl + j][e];
            _Float16 hh = (_Float16)f;
            o[j] = p ? (_Float16)(f - (float)hh) : hh;
        }
        *(f16x8*)(wst + (size_t)kt * 8192 + (size_t)slot * 8) = o;
    }
}

// LDS x buffer (8192 B each, 3 deep):
//   off(r,cs) = (r>>3)*2048 + (cs&1)*1024 + (r&7)*128 + (cs>>1)*16
//   stored chunk cs holds logical 16B-chunk c = (cs&1) | (((cs>>1)^(r&7))<<1)
__global__ __launch_bounds__(256, 2) void gate_main(const float* __restrict__ x,
        const ushort* __restrict__ wst, const float* __restrict__ bias,
        float* __restrict__ ws) {

    __shared__ __align__(16) char smem[3][8192];
    __shared__ float tmax[BM], tinv[BM];
    __shared__ float pp[4][NE];
    __shared__ float sg0[BM], sg1[BM];
    __shared__ int   si0[BM], si1[BM];

    const int tid = threadIdx.x, wave = tid >> 6, lane = tid & 63;
    const int l31 = lane & 31, khf = lane >> 5;
    const int s = wave;                // K-step owner (0..3)
    const int tb = blockIdx.x * BM;
    const int blk = blockIdx.x;

    f32x16 acc0, acc1;                 // expert halves 0,1
    #pragma unroll
    for (int i = 0; i < 16; i++) { acc0[i] = 0.0f; acc1[i] = 0.0f; }

    auto issue_x = [&](char* B, int kt) {
        #pragma unroll
        for (int q = 0; q < 2; q++) {
            int cs = ((lane & 7) << 1) | q;              // stored chunk
            int r  = (wave << 3) | (lane >> 3);          // row 0..31
            int cl = (cs & 1) | ((((cs >> 1) ^ (r & 7))) << 1);
            const float* src = x + (size_t)(tb + r) * DIM + kt * 64 + cl * 4;
            __builtin_amdgcn_global_load_lds(
                (const __attribute__((address_space(1))) uint*)src,
                (__attribute__((address_space(3))) uint*)
                    (B + wave * 2048 + q * 1024 + lane * 16), 16, 0, 0);
        }
    };

    // x-fragment read address (kt-independent): logical chunks c0, c0+1
    const int c0h = s * 2 + khf;       // (c0>>1) with c0 = s*4+khf*2
    const uint abase = (uint)(l31 >> 3) * 2048 + (uint)(l31 & 7) * 128
                     + (uint)((c0h ^ (l31 & 7)) * 16);

    // prologue: depth-2 x prefetch
    issue_x(smem[0], 0);
    issue_x(smem[1], 1);

    for (int kt = 0; kt < NKT; kt++) {
        asm volatile("s_waitcnt vmcnt(2)" ::: "memory");
        __builtin_amdgcn_s_barrier();
        const char* B = smem[kt % 3];
        // ---- W fragments for this wave's k-step: L2 -> regs, issued FIRST
        const ushort* wk = wst + (size_t)kt * 8192 + (size_t)s * 2048 + lane * 8;
        f16x8 wh0 = *(const f16x8*)(wk);          // p0 eh0
        f16x8 wh1 = *(const f16x8*)(wk + 512);    // p0 eh1
        f16x8 wm0 = *(const f16x8*)(wk + 1024);   // p1 eh0
        f16x8 wm1 = *(const f16x8*)(wk + 1536);   // p1 eh1
        __builtin_amdgcn_sched_barrier(0);        // pin W issue before x prefetch
        // ---- next-next x tile prefetch (newer than W => W waits don't drain it)
        if (kt + 2 < NKT) issue_x(smem[(kt + 2) % 3], kt + 2);
        // ---- x fragment from LDS + f16 2-plane split
        float4 A0 = *(const float4*)(B + abase);
        float4 A1 = *(const float4*)(B + abase + 1024);
        f16x8 ah, am;
        {
            float f[8] = {A0.x, A0.y, A0.z, A0.w, A1.x, A1.y, A1.z, A1.w};
            #pragma unroll
            for (int j = 0; j < 8; j++) {
                float v = 512.0f * f[j];
                _Float16 hh = (_Float16)v;
                ah[j] = hh;
                am[j] = (_Float16)(v - (float)hh);
            }
        }
        __builtin_amdgcn_s_setprio(1);
        acc0 = __builtin_amdgcn_mfma_f32_32x32x16_f16(ah, wh0, acc0, 0, 0, 0);
        acc1 = __builtin_amdgcn_mfma_f32_32x32x16_f16(ah, wh1, acc1, 0, 0, 0);
        acc0 = __builtin_amdgcn_mfma_f32_32x32x16_f16(am, wh0, acc0, 0, 0, 0);
        acc1 = __builtin_amdgcn_mfma_f32_32x32x16_f16(am, wh1, acc1, 0, 0, 0);
        acc0 = __builtin_amdgcn_mfma_f32_32x32x16_f16(ah, wm0, acc0, 0, 0, 0);
        acc1 = __builtin_amdgcn_mfma_f32_32x32x16_f16(ah, wm1, acc1, 0, 0, 0);
        __builtin_amdgcn_s_setprio(0);
    }
    __syncthreads();

    // epilogue: sequential cross-wave K reduction into lgf (aliases smem)
    // C/D: col = eh*32 + (lane&31), row = (reg&3) + 8*(reg>>2) + 4*khf
    float* lgf = (float*)smem;         // lg[32][68] = 8704 B < 24576 B
    const float scale = 1.0f / 2097152.0f;   // 2^-21 = 1/(512*4096)
    for (int p = 0; p < 4; p++) {
        if (s == p) {
            float b0 = bias[l31], b1 = bias[32 + l31];
            #pragma unroll
            for (int r = 0; r < 16; r++) {
                int row = (r & 3) + 8 * (r >> 2) + 4 * khf;
                if (p == 0) {
                    lgf[row * 68 + l31]      = acc0[r] * scale + b0;
                    lgf[row * 68 + 32 + l31] = acc1[r] * scale + b1;
                } else {
                    lgf[row * 68 + l31]      += acc0[r] * scale;
                    lgf[row * 68 + 32 + l31] += acc1[r] * scale;
                }
            }
        }
        __syncthreads();
    }

    // per-token softmax + top-2 (threads 0..31) — no atomics
    if (tid < BM) {
        const int t = tid;
        float m = -INFINITY;
        #pragma unroll
        for (int e = 0; e < NE; e++) m = fmaxf(m, lgf[t * 68 + e]);
        float sum = 0.0f;
        float v0 = -INFINITY, v1 = -INFINITY;
        int i0 = 0, i1 = 1;
        #pragma unroll
        for (int e = 0; e < NE; e++) {
            float l = lgf[t * 68 + e];
            sum += expf(l - m);
            if (l > v0) { v1 = v0; i1 = i0; v0 = l; i0 = e; }
            else if (l > v1) { v1 = l; i1 = e; }
        }
        float inv = 1.0f / sum;
        tmax[t] = m; tinv[t] = inv;
        float g0 = expf(v0 - m) * inv;
        float g1 = expf(v1 - m) * inv;
        sg0[t] = g0; sg1[t] = g1; si0[t] = i0; si1[t] = i1;
        float4 mt4;
        mt4.x = __int_as_float(i0);
        mt4.y = __int_as_float(i1);
        mt4.z = g0; mt4.w = g1;
        ((float4*)(ws + WS_META))[tb + t] = mt4;
    }
    __syncthreads();

    // per-expert gate-score partial sums (density_proxy numerator)
    {
        int e = tid & 63;
        int grp = tid >> 6;    // 0..3, 8 tokens each
        float p = 0.0f;
        #pragma unroll
        for (int r = 0; r < 8; r++) {
            int t = grp * 8 + r;
            p += expf(lgf[t * 68 + e] - tmax[t]) * tinv[t];
        }
        pp[grp][e] = p;
    }
    __syncthreads();

    // deterministic per-block partials: [blk][0:64)=denom, [64:128)=proxy, [128:192)=count
    if (tid < NE) {
        int e = tid;
        float d = 0.0f, c = 0.0f;
        #pragma unroll
        for (int t = 0; t < BM; t++) {
            if (si0[t] == e) { d += sg0[t]; c += 1.0f; }
            if (si1[t] == e) { d += sg1[t]; c += 1.0f; }
        }
        float pr = pp[0][e] + pp[1][e] + pp[2][e] + pp[3][e];
        float* P = ws + WS_PART + (size_t)blk * 192;
        P[e]       = d;
        P[64 + e]  = pr;
        P[128 + e] = c;
    }
}

// finals: ws[0:64)=denom, ws[64:128)=proxy, ws[128:192)=count
__global__ __launch_bounds__(64) void gate_reduce(const float* __restrict__ part,
                                                  float* __restrict__ ws) {
    const int f = blockIdx.x;      // 0..191
    const int lane = threadIdx.x;  // 0..63
    float s = 0.0f;
    #pragma unroll
    for (int j = 0; j < 8; j++)
        s += part[(size_t)(lane * 8 + j) * 192 + f];
    #pragma unroll
    for (int off = 32; off; off >>= 1) s += __shfl_down(s, off);
    if (lane == 0) ws[f] = s;
}

__global__ __launch_bounds__(256) void gate_write(const float* __restrict__ ws,
                                                  float* __restrict__ out) {
    const float CAP = 16384.0f;
    int tid = threadIdx.x;
    int tl = tid >> 4;
    int e4 = (tid & 15) * 4;
    int t = blockIdx.x * 16 + tl;
    float4 mt = ((const float4*)(ws + WS_META))[t];
    int i0 = __float_as_int(mt.x), i1 = __float_as_int(mt.y);
    float s0 = mt.z * CAP / (ws[i0] + 1e-6f);
    float s1 = mt.w * CAP / (ws[i1] + 1e-6f);
    float4 v = {0.0f, 0.0f, 0.0f, 0.0f};
    float* vp = (float*)&v;
    #pragma unroll
    for (int j = 0; j < 4; j++) {
        int e = e4 + j;
        vp[j] = (e == i0) ? s0 : ((e == i1) ? s1 : 0.0f);
    }
    *(float4*)(out + (size_t)t * NE + e4) = v;
    // loss folded in: block 0, first wave
    if (blockIdx.x == 0 && tid < 64) {
        float lv = ws[64 + tid] * ws[128 + tid];
        #pragma unroll
        for (int off = 32; off; off >>= 1) lv += __shfl_down(lv, off);
        if (tid == 0)
            out[(size_t)TOKENS * NE] = 64.0f * lv / (16384.0f * 16384.0f);
    }
}

extern "C" void kernel_launch(void* const* d_in, const int* in_sizes, int n_in,
                              void* d_out, int out_size, void* d_ws, size_t ws_size,
                              hipStream_t stream) {
    const float* x = (const float*)d_in[0];
    const float* W = (const float*)d_in[1];
    const float* b = (const float*)d_in[2];
    float* out = (float*)d_out;
    float* ws = (float*)d_ws;
    ushort* wst = (ushort*)(ws + WS_WST);

    hipLaunchKernelGGL(wconv, dim3(64), dim3(256), 0, stream, W, wst);
    hipLaunchKernelGGL(gate_main, dim3(NBLK), dim3(256), 0, stream, x, wst, b, ws);
    hipLaunchKernelGGL(gate_reduce, dim3(192), dim3(64), 0, stream,
                       ws + WS_PART, ws);
    hipLaunchKernelGGL(gate_write, dim3(TOKENS / 16), dim3(256), 0, stream, ws, out);
}

// Round 11
// 85.914 us; speedup vs baseline: 1.1268x; 1.0480x over previous
//
#include <hip/hip_runtime.h>
#include <math.h>

#define TOKENS 16384
#define DIM 4096
#define NE 64
#define BM 32
#define NKT2 32                            // 128-wide K tiles
#define NBLK 512

// ws float offsets
#define WS_META  256                       // float4 per token: 65536 floats
#define WS_PART  65792                     // 512 blocks x 192 floats
#define WS_WST   164096                    // 524288 ushorts = W f16 2-plane frag-linear

typedef __attribute__((ext_vector_type(8))) _Float16 f16x8;
typedef __attribute__((ext_vector_type(16))) float f32x16;

// W [4096][64] f32 -> wst: per kt64, 16 fragments of 1 KB.
//   frag = s64*4 + p*2 + eh ; offset = kt64*8192 + s64*2048 + p*1024 + eh*512 + lane*8
//   value = plane-p f16 of 4096*W[kt64*64 + s64*16 + (lane>>5)*8 + j][eh*32 + (lane&31)]
// 256 blocks: block = kt64*4 + s64
__global__ __launch_bounds__(64) void wconv(const float* __restrict__ W,
                                            ushort* __restrict__ wst) {
    const int b = blockIdx.x;
    const int kt = b >> 2, s = b & 3;
    const int lane = threadIdx.x;
    const int l31 = lane & 31, khf = lane >> 5;
    #pragma unroll
    for (int eh = 0; eh < 2; eh++) {
        int e = eh * 32 + l31;
        f16x8 H, M;
        #pragma unroll
        for (int j = 0; j < 8; j++) {
            float f = 4096.0f * W[(size_t)(kt * 64 + s * 16 + khf * 8 + j) * NE + e];
            _Float16 hh = (_Float16)f;
            H[j] = hh;
            M[j] = (_Float16)(f - (float)hh);
        }
        size_t o = (size_t)kt * 8192 + (size_t)s * 2048 + (size_t)eh * 512
                 + (size_t)lane * 8;
        *(f16x8*)(wst + o)        = H;     // p = 0
        *(f16x8*)(wst + o + 1024) = M;     // p = 1
    }
}

// LDS x buffer (16 KB each, 3 deep), BK=128:
//   byte(r, cs) = (r>>3)*4096 + (r&7)*128 + (cs>>3)*1024 + (cs&7)*16
//   stored chunk cs holds logical 16B-chunk c = (cs&24) | ((cs&7)^(r&7))
__global__ __launch_bounds__(256, 2) void gate_main(const float* __restrict__ x,
        const ushort* __restrict__ wst, const float* __restrict__ bias,
        float* __restrict__ ws) {

    __shared__ __align__(16) char smem[3][16384];
    __shared__ float tmax[BM], tinv[BM];
    __shared__ float pp[4][NE];
    __shared__ float sg0[BM], sg1[BM];
    __shared__ int   si0[BM], si1[BM];

    const int tid = threadIdx.x, wave = tid >> 6, lane = tid & 63;
    const int l31 = lane & 31, khf = lane >> 5;
    const int s = wave;                // K-slice owner (32 k each)
    const int tb = blockIdx.x * BM;
    const int blk = blockIdx.x;

    f32x16 acc0, acc1;                 // expert halves
    #pragma unroll
    for (int i = 0; i < 16; i++) { acc0[i] = 0.0f; acc1[i] = 0.0f; }

    auto issue_x = [&](char* B, int kt) {
        #pragma unroll
        for (int q = 0; q < 4; q++) {
            int r = (wave << 3) | (lane >> 3);
            int c = q * 8 + ((lane & 7) ^ (r & 7));
            const float* src = x + (size_t)(tb + r) * DIM + kt * 128 + c * 4;
            __builtin_amdgcn_global_load_lds(
                (const __attribute__((address_space(1))) uint*)src,
                (__attribute__((address_space(3))) uint*)
                    (B + wave * 4096 + q * 1024 + lane * 16), 16, 0, 0);
        }
    };

    // A-fragment read base (row = l31): + ((c7 ^ (l31&7)))*16 per logical chunk
    const uint abase = (uint)(l31 >> 3) * 4096 + (uint)(l31 & 7) * 128
                     + (uint)s * 1024;
    const uint rx = (uint)(l31 & 7);

    auto split8 = [&](float4 A0, float4 A1, f16x8& ah, f16x8& am) {
        float f[8] = {A0.x, A0.y, A0.z, A0.w, A1.x, A1.y, A1.z, A1.w};
        #pragma unroll
        for (int j = 0; j < 8; j++) {
            float v = 512.0f * f[j];
            _Float16 hh = (_Float16)v;
            ah[j] = hh;
            am[j] = (_Float16)(v - (float)hh);
        }
    };

    auto body = [&](int kt) {
        const char* B = smem[kt % 3];
        // ---- W fragments for both 16-k steps: L2 -> regs, pinned first
        const int idx0 = s * 2, idx1 = s * 2 + 1;
        const ushort* wk0 = wst + (size_t)(2 * kt + (idx0 >> 2)) * 8192
                          + (size_t)(idx0 & 3) * 2048 + lane * 8;
        const ushort* wk1 = wst + (size_t)(2 * kt + (idx1 >> 2)) * 8192
                          + (size_t)(idx1 & 3) * 2048 + lane * 8;
        f16x8 wA0 = *(const f16x8*)(wk0);          // si0 p0 eh0
        f16x8 wA1 = *(const f16x8*)(wk0 + 512);    // si0 p0 eh1
        f16x8 wA2 = *(const f16x8*)(wk0 + 1024);   // si0 p1 eh0
        f16x8 wA3 = *(const f16x8*)(wk0 + 1536);   // si0 p1 eh1
        f16x8 wB0 = *(const f16x8*)(wk1);
        f16x8 wB1 = *(const f16x8*)(wk1 + 512);
        f16x8 wB2 = *(const f16x8*)(wk1 + 1024);
        f16x8 wB3 = *(const f16x8*)(wk1 + 1536);
        __builtin_amdgcn_sched_barrier(0);         // pin W issue before x prefetch
        if (kt + 2 < NKT2) issue_x(smem[(kt + 2) % 3], kt + 2);
        // ---- si = 0
        {
            uint c7 = (uint)(khf * 2);
            float4 A0 = *(const float4*)(B + abase + ((c7 ^ rx) * 16));
            float4 A1 = *(const float4*)(B + abase + (((c7 + 1) ^ rx) * 16));
            f16x8 ah, am;
            split8(A0, A1, ah, am);
            __builtin_amdgcn_s_setprio(1);
            acc0 = __builtin_amdgcn_mfma_f32_32x32x16_f16(ah, wA0, acc0, 0, 0, 0);
            acc1 = __builtin_amdgcn_mfma_f32_32x32x16_f16(ah, wA1, acc1, 0, 0, 0);
            acc0 = __builtin_amdgcn_mfma_f32_32x32x16_f16(am, wA0, acc0, 0, 0, 0);
            acc1 = __builtin_amdgcn_mfma_f32_32x32x16_f16(am, wA1, acc1, 0, 0, 0);
            acc0 = __builtin_amdgcn_mfma_f32_32x32x16_f16(ah, wA2, acc0, 0, 0, 0);
            acc1 = __builtin_amdgcn_mfma_f32_32x32x16_f16(ah, wA3, acc1, 0, 0, 0);
            __builtin_amdgcn_s_setprio(0);
        }
        // ---- si = 1
        {
            uint c7 = (uint)(4 + khf * 2);
            float4 A0 = *(const float4*)(B + abase + ((c7 ^ rx) * 16));
            float4 A1 = *(const float4*)(B + abase + (((c7 + 1) ^ rx) * 16));
            f16x8 ah, am;
            split8(A0, A1, ah, am);
            __builtin_amdgcn_s_setprio(1);
            acc0 = __builtin_amdgcn_mfma_f32_32x32x16_f16(ah, wB0, acc0, 0, 0, 0);
            acc1 = __builtin_amdgcn_mfma_f32_32x32x16_f16(ah, wB1, acc1, 0, 0, 0);
            acc0 = __builtin_amdgcn_mfma_f32_32x32x16_f16(am, wB0, acc0, 0, 0, 0);
            acc1 = __builtin_amdgcn_mfma_f32_32x32x16_f16(am, wB1, acc1, 0, 0, 0);
            acc0 = __builtin_amdgcn_mfma_f32_32x32x16_f16(ah, wB2, acc0, 0, 0, 0);
            acc1 = __builtin_amdgcn_mfma_f32_32x32x16_f16(ah, wB3, acc1, 0, 0, 0);
            __builtin_amdgcn_s_setprio(0);
        }
    };

    // prologue: depth-2 prefetch
    issue_x(smem[0], 0);
    issue_x(smem[1], 1);

    for (int kt = 0; kt < NKT2 - 1; kt++) {
        asm volatile("s_waitcnt vmcnt(4)" ::: "memory");
        __builtin_amdgcn_s_barrier();
        body(kt);
    }
    asm volatile("s_waitcnt vmcnt(0)" ::: "memory");
    __builtin_amdgcn_s_barrier();
    body(NKT2 - 1);
    __syncthreads();

    // epilogue: sequential cross-wave K reduction into lgf (aliases smem)
    // C/D: col = eh*32 + (lane&31), row = (reg&3) + 8*(reg>>2) + 4*khf
    float* lgf = (float*)smem;         // lg[32][68] = 8704 B
    const float scale = 1.0f / 2097152.0f;   // 2^-21 = 1/(512*4096)
    for (int p = 0; p < 4; p++) {
        if (s == p) {
            float b0 = bias[l31], b1 = bias[32 + l31];
            #pragma unroll
            for (int r = 0; r < 16; r++) {
                int row = (r & 3) + 8 * (r >> 2) + 4 * khf;
                if (p == 0) {
                    lgf[row * 68 + l31]      = acc0[r] * scale + b0;
                    lgf[row * 68 + 32 + l31] = acc1[r] * scale + b1;
                } else {
                    lgf[row * 68 + l31]      += acc0[r] * scale;
                    lgf[row * 68 + 32 + l31] += acc1[r] * scale;
                }
            }
        }
        __syncthreads();
    }

    // per-token softmax + top-2 (threads 0..31) — no atomics
    if (tid < BM) {
        const int t = tid;
        float m = -INFINITY;
        #pragma unroll
        for (int e = 0; e < NE; e++) m = fmaxf(m, lgf[t * 68 + e]);
        float sum = 0.0f;
        float v0 = -INFINITY, v1 = -INFINITY;
        int i0 = 0, i1 = 1;
        #pragma unroll
        for (int e = 0; e < NE; e++) {
            float l = lgf[t * 68 + e];
            sum += expf(l - m);
            if (l > v0) { v1 = v0; i1 = i0; v0 = l; i0 = e; }
            else if (l > v1) { v1 = l; i1 = e; }
        }
        float inv = 1.0f / sum;
        tmax[t] = m; tinv[t] = inv;
        float g0 = expf(v0 - m) * inv;
        float g1 = expf(v1 - m) * inv;
        sg0[t] = g0; sg1[t] = g1; si0[t] = i0; si1[t] = i1;
        float4 mt4;
        mt4.x = __int_as_float(i0);
        mt4.y = __int_as_float(i1);
        mt4.z = g0; mt4.w = g1;
        ((float4*)(ws + WS_META))[tb + t] = mt4;
    }
    __syncthreads();

    // per-expert gate-score partial sums (density_proxy numerator)
    {
        int e = tid & 63;
        int grp = tid >> 6;    // 0..3, 8 tokens each
        float p = 0.0f;
        #pragma unroll
        for (int r = 0; r < 8; r++) {
            int t = grp * 8 + r;
            p += expf(lgf[t * 68 + e] - tmax[t]) * tinv[t];
        }
        pp[grp][e] = p;
    }
    __syncthreads();

    // deterministic per-block partials: [blk][0:64)=denom, [64:128)=proxy, [128:192)=count
    if (tid < NE) {
        int e = tid;
        float d = 0.0f, c = 0.0f;
        #pragma unroll
        for (int t = 0; t < BM; t++) {
            if (si0[t] == e) { d += sg0[t]; c += 1.0f; }
            if (si1[t] == e) { d += sg1[t]; c += 1.0f; }
        }
        float pr = pp[0][e] + pp[1][e] + pp[2][e] + pp[3][e];
        float* P = ws + WS_PART + (size_t)blk * 192;
        P[e]       = d;
        P[64 + e]  = pr;
        P[128 + e] = c;
    }
}

// finals: ws[0:64)=denom, ws[64:128)=proxy, ws[128:192)=count
__global__ __launch_bounds__(64) void gate_reduce(const float* __restrict__ part,
                                                  float* __restrict__ ws) {
    const int f = blockIdx.x;      // 0..191
    const int lane = threadIdx.x;  // 0..63
    float s = 0.0f;
    #pragma unroll
    for (int j = 0; j < 8; j++)
        s += part[(size_t)(lane * 8 + j) * 192 + f];
    #pragma unroll
    for (int off = 32; off; off >>= 1) s += __shfl_down(s, off);
    if (lane == 0) ws[f] = s;
}

__global__ __launch_bounds__(256) void gate_write(const float* __restrict__ ws,
                                                  float* __restrict__ out) {
    const float CAP = 16384.0f;
    int tid = threadIdx.x;
    int tl = tid >> 4;
    int e4 = (tid & 15) * 4;
    int t = blockIdx.x * 16 + tl;
    float4 mt = ((const float4*)(ws + WS_META))[t];
    int i0 = __float_as_int(mt.x), i1 = __float_as_int(mt.y);
    float s0 = mt.z * CAP / (ws[i0] + 1e-6f);
    float s1 = mt.w * CAP / (ws[i1] + 1e-6f);
    float4 v = {0.0f, 0.0f, 0.0f, 0.0f};
    float* vp = (float*)&v;
    #pragma unroll
    for (int j = 0; j < 4; j++) {
        int e = e4 + j;
        vp[j] = (e == i0) ? s0 : ((e == i1) ? s1 : 0.0f);
    }
    *(float4*)(out + (size_t)t * NE + e4) = v;
    // loss folded in: block 0, first wave
    if (blockIdx.x == 0 && tid < 64) {
        float lv = ws[64 + tid] * ws[128 + tid];
        #pragma unroll
        for (int off = 32; off; off >>= 1) lv += __shfl_down(lv, off);
        if (tid == 0)
            out[(size_t)TOKENS * NE] = 64.0f * lv / (16384.0f * 16384.0f);
    }
}

extern "C" void kernel_launch(void* const* d_in, const int* in_sizes, int n_in,
                              void* d_out, int out_size, void* d_ws, size_t ws_size,
                              hipStream_t stream) {
    const float* x = (const float*)d_in[0];
    const float* W = (const float*)d_in[1];
    const float* b = (const float*)d_in[2];
    float* out = (float*)d_out;
    float* ws = (float*)d_ws;
    ushort* wst = (ushort*)(ws + WS_WST);

    hipLaunchKernelGGL(wconv, dim3(256), dim3(64), 0, stream, W, wst);
    hipLaunchKernelGGL(gate_main, dim3(NBLK), dim3(256), 0, stream, x, wst, b, ws);
    hipLaunchKernelGGL(gate_reduce, dim3(192), dim3(64), 0, stream,
                       ws + WS_PART, ws);
    hipLaunchKernelGGL(gate_write, dim3(TOKENS / 16), dim3(256), 0, stream, ws, out);
}